// Round 1
// baseline (187.193 us; speedup 1.0000x reference)
//
#include <hip/hip_runtime.h>
#include <hip/hip_bf16.h>
#include <stdint.h>

#define KDIM 4096
#define NDIM 4096
#define MDIM 4096
#define TILE 128
#define BK 64

typedef __attribute__((ext_vector_type(8))) short bf16x8;
typedef __attribute__((ext_vector_type(4))) float f32x4;

// ---------- helpers ----------

__device__ __forceinline__ unsigned short bf16bits(float f) {
    union { float f; uint32_t u; } c; c.f = f;
    uint32_t u = c.u;
    uint32_t r = (u + 0x7fffu + ((u >> 16) & 1u)) >> 16;   // RNE
    return (unsigned short)r;
}

// Faithful FP4 E2M1 quant-dequant (matches the reference's float math,
// including clip-saturating mantissa and round-half-even).
__device__ __forceinline__ float fp4qd(float x) {
    float a = fabsf(x);
    if (a == 0.0f) return 0.0f;
    float e = floorf(log2f(a));
    float val;
    if (e < 0.0f) {                       // subnormal path
        float mant = fminf(fmaxf(rintf(a * 2.0f), 0.0f), 1.0f);
        val = mant * 0.5f;
    } else {
        float ec = fminf(e, 2.0f);
        float p  = exp2f(ec);             // exact: 1,2,4
        float mant = fminf(fmaxf(rintf((a / p - 1.0f) * 2.0f), 0.0f), 1.0f);
        val = (1.0f + 0.5f * mant) * p;
    }
    return (x < 0.0f) ? -val : val;
}

__device__ __forceinline__ void gld16(void* lds, const void* g) {
    __builtin_amdgcn_global_load_lds(
        (const __attribute__((address_space(1))) unsigned int*)g,
        (__attribute__((address_space(3))) unsigned int*)lds,
        16, 0, 0);
}

// ---------- kernel 1: weight quant-dequant -> bf16 ----------
// one wave per group of 128; block = 4 waves
__global__ __launch_bounds__(256) void wdeq_kernel(const float* __restrict__ W,
                                                   unsigned short* __restrict__ Wq) {
    int grp = blockIdx.x * 4 + (threadIdx.x >> 6);
    int l = threadIdx.x & 63;
    const float* gp = W + (size_t)grp * 128 + l * 2;
    float2 v = *(const float2*)gp;
    float am = fmaxf(fabsf(v.x), fabsf(v.y));
    #pragma unroll
    for (int s = 32; s; s >>= 1) am = fmaxf(am, __shfl_xor(am, s));
    float scale = (am == 0.0f) ? 1.0f : am / 6.0f;   // exact f32 div, as ref
    float q0 = fp4qd(v.x / scale) * scale;
    float q1 = fp4qd(v.y / scale) * scale;
    ushort2 o;
    o.x = bf16bits(q0);
    o.y = bf16bits(q1);
    *(ushort2*)(Wq + (size_t)grp * 128 + l * 2) = o;
}

// ---------- kernel 2: x f32 -> bf16 ----------
__global__ __launch_bounds__(256) void xcvt_kernel(const float* __restrict__ X,
                                                   unsigned short* __restrict__ Xb) {
    size_t i = (size_t)(blockIdx.x * 256 + threadIdx.x) * 4;
    float4 v = *(const float4*)(X + i);
    ushort4 o;
    o.x = bf16bits(v.x); o.y = bf16bits(v.y);
    o.z = bf16bits(v.z); o.w = bf16bits(v.w);
    *(ushort4*)(Xb + i) = o;
}

// ---------- kernel 3: C = A @ B^T + bias ----------
// A: [M][K] bf16, B: [N][K] bf16 (both K-contiguous), C: [M][N] f32.
// 128x128 tile, BK=64, 4 waves (2x2 of 64x64), 16x16x32 bf16 MFMA.
// LDS staged via global_load_lds(16B) with XOR swizzle (chunk ^= row&7):
// linear LDS dest + pre-swizzled global source + swizzled ds_read.
__global__ __launch_bounds__(256) void gemm_bt_bias(const unsigned short* __restrict__ A,
                                                    const unsigned short* __restrict__ B,
                                                    const float* __restrict__ bias,
                                                    float* __restrict__ C) {
    __shared__ __attribute__((aligned(16))) char smem[2][TILE * BK * 2]; // 16KB A + 16KB B

    const int t = threadIdx.x;
    const int w = t >> 6;
    const int l = t & 63;
    const int wu = __builtin_amdgcn_readfirstlane(w);   // wave-uniform for LDS bases

    const int brow = blockIdx.y * TILE;   // M tile
    const int bcol = blockIdx.x * TILE;   // N tile

    // --- staging addresses ---
    // gl_lds issue i (i=0..3) of wave w covers LDS chunks [(i*4+w)*64, +64)
    // chunk c: row r = c>>3, slot c&7; element stored there is global
    // col-chunk j = slot ^ (r&7)  (r&7 == l>>3 since bases are 8-row aligned)
    const int lr8 = l >> 3;                    // 0..7
    const int sj  = ((l & 7) ^ lr8) * 8;       // swizzled source col (elements)
    const unsigned short* gA[4];
    const unsigned short* gB[4];
    char* ldsA[4];
    char* ldsB[4];
    #pragma unroll
    for (int i = 0; i < 4; ++i) {
        int ri = (i * 4 + wu) * 8 + lr8;       // row within tile
        gA[i] = A + (size_t)(brow + ri) * KDIM + sj;
        gB[i] = B + (size_t)(bcol + ri) * KDIM + sj;
        ldsA[i] = &smem[0][(i * 4 + wu) * 1024];
        ldsB[i] = &smem[1][(i * 4 + wu) * 1024];
    }

    // --- fragment read addressing ---
    const int fr = l & 15;     // fragment row (LDS tile row within 16-row sub)
    const int fq = l >> 4;     // k-chunk 0..3
    const int sA = (w >> 1) * 64;   // wave M offset
    const int sB = (w & 1) * 64;    // wave N offset

    f32x4 acc[4][4];
    #pragma unroll
    for (int m = 0; m < 4; ++m)
        #pragma unroll
        for (int n = 0; n < 4; ++n)
            acc[m][n] = f32x4{0.f, 0.f, 0.f, 0.f};

    for (int kt = 0; kt < KDIM / BK; ++kt) {
        #pragma unroll
        for (int i = 0; i < 4; ++i) {
            gld16(ldsA[i], gA[i]); gA[i] += BK;
            gld16(ldsB[i], gB[i]); gB[i] += BK;
        }
        __syncthreads();   // compiler emits vmcnt(0) drain before barrier

        #pragma unroll
        for (int ks = 0; ks < 2; ++ks) {
            bf16x8 av[4], bv[4];
            #pragma unroll
            for (int m = 0; m < 4; ++m) {
                int r = sA + m * 16 + fr;
                av[m] = *(const bf16x8*)&smem[0][r * 128 + (((ks * 4 + fq) ^ (fr & 7)) * 16)];
            }
            #pragma unroll
            for (int n = 0; n < 4; ++n) {
                int r = sB + n * 16 + fr;
                bv[n] = *(const bf16x8*)&smem[1][r * 128 + (((ks * 4 + fq) ^ (fr & 7)) * 16)];
            }
            #pragma unroll
            for (int m = 0; m < 4; ++m)
                #pragma unroll
                for (int n = 0; n < 4; ++n)
                    acc[m][n] = __builtin_amdgcn_mfma_f32_16x16x32_bf16(av[m], bv[n], acc[m][n], 0, 0, 0);
        }
        __syncthreads();   // all reads done before next stage overwrites
    }

    // --- epilogue: C[row][col] = acc + bias[col] ---
    // C/D layout: col = lane&15, row = (lane>>4)*4 + reg
    float bb[4];
    #pragma unroll
    for (int n = 0; n < 4; ++n) bb[n] = bias[bcol + sB + n * 16 + fr];
    #pragma unroll
    for (int m = 0; m < 4; ++m) {
        #pragma unroll
        for (int q = 0; q < 4; ++q) {
            int row = brow + sA + m * 16 + fq * 4 + q;
            float* crow = C + (size_t)row * NDIM + bcol + sB;
            #pragma unroll
            for (int n = 0; n < 4; ++n)
                crow[n * 16 + fr] = acc[m][n][q] + bb[n];
        }
    }
}

// ---------- launch ----------
extern "C" void kernel_launch(void* const* d_in, const int* in_sizes, int n_in,
                              void* d_out, int out_size, void* d_ws, size_t ws_size,
                              hipStream_t stream) {
    const float* x = (const float*)d_in[0];
    const float* w = (const float*)d_in[1];
    const float* b = (const float*)d_in[2];
    float* out = (float*)d_out;

    unsigned short* xb = (unsigned short*)d_ws;                         // 32 MB
    unsigned short* wq = xb + (size_t)NDIM * KDIM;                      // 32 MB

    xcvt_kernel<<<MDIM * KDIM / 4 / 256, 256, 0, stream>>>(x, xb);
    wdeq_kernel<<<NDIM * (KDIM / 128) / 4, 256, 0, stream>>>(w, wq);
    gemm_bt_bias<<<dim3(NDIM / TILE, MDIM / TILE), 256, 0, stream>>>(xb, wq, b, out);
}

// Round 2
// 157.832 us; speedup vs baseline: 1.1860x; 1.1860x over previous
//
#include <hip/hip_runtime.h>
#include <hip/hip_bf16.h>
#include <stdint.h>

#define KDIM 4096
#define NDIM 4096
#define MDIM 4096
#define BM 256
#define BN 256
#define BK 64

typedef __attribute__((ext_vector_type(8))) short bf16x8;
typedef __attribute__((ext_vector_type(4))) float f32x4;

// ---------- helpers ----------

__device__ __forceinline__ unsigned short bf16bits(float f) {
    union { float f; uint32_t u; } c; c.f = f;
    uint32_t u = c.u;
    uint32_t r = (u + 0x7fffu + ((u >> 16) & 1u)) >> 16;   // RNE
    return (unsigned short)r;
}

// Faithful FP4 E2M1 quant-dequant (matches reference float math).
__device__ __forceinline__ float fp4qd(float x) {
    float a = fabsf(x);
    if (a == 0.0f) return 0.0f;
    float e = floorf(log2f(a));
    float val;
    if (e < 0.0f) {                       // subnormal path
        float mant = fminf(fmaxf(rintf(a * 2.0f), 0.0f), 1.0f);
        val = mant * 0.5f;
    } else {
        float ec = fminf(e, 2.0f);
        float p  = exp2f(ec);             // exact: 1,2,4
        float mant = fminf(fmaxf(rintf((a / p - 1.0f) * 2.0f), 0.0f), 1.0f);
        val = (1.0f + 0.5f * mant) * p;
    }
    return (x < 0.0f) ? -val : val;
}

__device__ __forceinline__ void gld16(void* lds, const void* g) {
    __builtin_amdgcn_global_load_lds(
        (const __attribute__((address_space(1))) unsigned int*)g,
        (__attribute__((address_space(3))) unsigned int*)lds,
        16, 0, 0);
}

// ---------- kernel 1: weight quant-dequant -> bf16 ----------
__global__ __launch_bounds__(256) void wdeq_kernel(const float* __restrict__ W,
                                                   unsigned short* __restrict__ Wq) {
    int grp = blockIdx.x * 4 + (threadIdx.x >> 6);
    int l = threadIdx.x & 63;
    const float* gp = W + (size_t)grp * 128 + l * 2;
    float2 v = *(const float2*)gp;
    float am = fmaxf(fabsf(v.x), fabsf(v.y));
    #pragma unroll
    for (int s = 32; s; s >>= 1) am = fmaxf(am, __shfl_xor(am, s));
    float scale = (am == 0.0f) ? 1.0f : am / 6.0f;
    float q0 = fp4qd(v.x / scale) * scale;
    float q1 = fp4qd(v.y / scale) * scale;
    ushort2 o;
    o.x = bf16bits(q0);
    o.y = bf16bits(q1);
    *(ushort2*)(Wq + (size_t)grp * 128 + l * 2) = o;
}

// ---------- kernel 2: x f32 -> bf16 ----------
__global__ __launch_bounds__(256) void xcvt_kernel(const float* __restrict__ X,
                                                   unsigned short* __restrict__ Xb) {
    size_t i = (size_t)(blockIdx.x * 256 + threadIdx.x) * 4;
    float4 v = *(const float4*)(X + i);
    ushort4 o;
    o.x = bf16bits(v.x); o.y = bf16bits(v.y);
    o.z = bf16bits(v.z); o.w = bf16bits(v.w);
    *(ushort4*)(Xb + i) = o;
}

// ---------- kernel 3: 256x256-tile 8-phase GEMM  C = A @ B^T + bias ----------
// A: [M][K] bf16, B: [N][K] bf16, C: [M][N] f32.
// 8 waves (2M x 4N), per-wave 128x64 output, acc[8][4] of 16x16 frags.
// LDS: smem[buf][op(A/B)][half][16KB], 128 KiB total, 1 block/CU.
// Half-tile = [128 rows][64 cols bf16]; staged via 2x global_load_lds(16B)
// with chunk-XOR swizzle (slot = kc ^ (row&7)) -> conflict-free ds_read_b128.
// Per-iteration 8 phases (2 K-tiles); counted vmcnt(4) at P4/P8 only.

#define BAR()   __builtin_amdgcn_s_barrier()
#define LGKM0() asm volatile("s_waitcnt lgkmcnt(0)" ::: "memory")
#define VM4()   asm volatile("s_waitcnt vmcnt(4)" ::: "memory")
#define SCH0()  __builtin_amdgcn_sched_barrier(0)
#define PRIO(x) __builtin_amdgcn_s_setprio(x)

__global__ __launch_bounds__(512, 2) void gemm256(const unsigned short* __restrict__ A,
                                                  const unsigned short* __restrict__ B,
                                                  const float* __restrict__ bias,
                                                  float* __restrict__ C) {
    __shared__ __attribute__((aligned(16))) char smem[2][2][2][16384];
    char* sm = (char*)&smem[0][0][0][0];

    const int t = threadIdx.x;
    const int l = t & 63;
    const int w = __builtin_amdgcn_readfirstlane(t >> 6);  // 0..7
    const int wm = w >> 2;        // 0..1  (M half)
    const int wn = w & 3;         // 0..3  (N quarter)

    // bijective XCD swizzle (256 blocks, 8 XCDs)
    int bid = blockIdx.x;
    int swz = (bid & 7) * 32 + (bid >> 3);
    int brow = (swz >> 4) * BM;
    int bcol = (swz & 15) * BN;

    // ---- staging addresses (pre-swizzled global source, linear LDS dest) ----
    const int lr8  = l >> 3;                 // row in 8-row slab
    const int slot = l & 7;
    const int scol = (slot ^ lr8) << 3;      // swizzled source col (elements)
    const unsigned short* pA = A + (size_t)(brow + w * 8 + lr8) * KDIM + scol;
    const unsigned short* pB = B + (size_t)(bcol + w * 8 + lr8) * KDIM + scol;

    // stage one half-tile: op 0=A 1=B, half h, buffer b, K-tile kt
#define STAGE(b, op, h, kt) do {                                               \
    const unsigned short* _s = ((op) ? pB : pA)                                \
        + (size_t)(h) * 128 * KDIM + (size_t)(kt) * BK;                        \
    gld16(sm + (b) * 65536 + (op) * 32768 + (h) * 16384 + w * 1024, _s);       \
    gld16(sm + (b) * 65536 + (op) * 32768 + (h) * 16384 + 8192 + w * 1024,     \
          _s + (size_t)64 * KDIM);                                             \
} while (0)

    // ---- fragment read addressing ----
    const int fr  = l & 15;
    const int fq  = l >> 4;
    const int kx0 = ((fq    ) ^ (fr & 7)) << 4;   // ks=0 swizzled chunk byte
    const int kx1 = ((fq + 4) ^ (fr & 7)) << 4;   // ks=1
    const int frA = fr * 128;

#define RD_A(b, mh) do {                                                        \
    const char* _p = sm + (b) * 65536 + wm * 16384 + (mh) * 8192 + frA;         \
    _Pragma("unroll")                                                           \
    for (int m = 0; m < 4; ++m) {                                               \
        a[m][0] = *(const bf16x8*)(_p + m * 2048 + kx0);                        \
        a[m][1] = *(const bf16x8*)(_p + m * 2048 + kx1);                        \
    }                                                                           \
} while (0)

#define RD_B(b, nh, arr) do {                                                   \
    const char* _p = sm + (b) * 65536 + 32768 + (wn >> 1) * 16384               \
                     + (wn & 1) * 8192 + (nh) * 4096 + frA;                     \
    _Pragma("unroll")                                                           \
    for (int n = 0; n < 2; ++n) {                                               \
        arr[n][0] = *(const bf16x8*)(_p + n * 2048 + kx0);                      \
        arr[n][1] = *(const bf16x8*)(_p + n * 2048 + kx1);                      \
    }                                                                           \
} while (0)

#define MM(mh, nh, arr)                                                         \
    _Pragma("unroll")                                                           \
    for (int m = 0; m < 4; ++m)                                                 \
        _Pragma("unroll")                                                       \
        for (int n = 0; n < 2; ++n)                                             \
            _Pragma("unroll")                                                   \
            for (int ks = 0; ks < 2; ++ks)                                      \
                acc[(mh) * 4 + m][(nh) * 2 + n] =                               \
                    __builtin_amdgcn_mfma_f32_16x16x32_bf16(                    \
                        a[m][ks], arr[n][ks], acc[(mh) * 4 + m][(nh) * 2 + n],  \
                        0, 0, 0);

    f32x4 acc[8][4];
    #pragma unroll
    for (int m = 0; m < 8; ++m)
        #pragma unroll
        for (int n = 0; n < 4; ++n)
            acc[m][n] = f32x4{0.f, 0.f, 0.f, 0.f};

    bf16x8 a[4][2], bA[2][2], bB[2][2];

    // ---- prologue: t0 all 4 half-tiles + t1.B0 + t1.A0 (12 loads) ----
    STAGE(0, 0, 0, 0); STAGE(0, 0, 1, 0); STAGE(0, 1, 0, 0); STAGE(0, 1, 1, 0);
    STAGE(1, 1, 0, 1); STAGE(1, 0, 0, 1);
    VM4();            // t0 fully landed; t1.B0/A0 in flight
    BAR(); SCH0();

    // ---- main loop: iteration computes K-tiles 2it (buf0) and 2it+1 (buf1) ----
    for (int it = 0; it < 32; ++it) {
        const int k1 = 2 * it + 1;
        const int k2 = (2 * it + 2) & 63;   // wrap on last iter (garbage never read)
        const int k3 = (2 * it + 3) & 63;

        // P1: reads buf0 A-mh0 + B-nh0 ; stage (t+1).A1
        RD_A(0, 0); RD_B(0, 0, bA); STAGE(1, 0, 1, k1);
        BAR(); LGKM0(); SCH0(); PRIO(1); MM(0, 0, bA); PRIO(0); BAR(); SCH0();
        // P2: reads buf0 B-nh1 ; stage (t+1).B1
        RD_B(0, 1, bB); STAGE(1, 1, 1, k1);
        BAR(); LGKM0(); SCH0(); PRIO(1); MM(0, 1, bB); PRIO(0); BAR(); SCH0();
        // P3: reads buf0 A-mh1 ; stage (t+2).B0
        RD_A(0, 1); STAGE(0, 1, 0, k2);
        BAR(); LGKM0(); SCH0(); PRIO(1); MM(1, 1, bB); PRIO(0); BAR(); SCH0();
        // P4: stage (t+2).A0 ; counted vmcnt before buf1 reads
        STAGE(0, 0, 0, k2);
        BAR(); SCH0(); PRIO(1); MM(1, 0, bA); PRIO(0); VM4(); BAR(); SCH0();

        // P5: reads buf1 A-mh0 + B-nh0 ; stage (t+2).A1
        RD_A(1, 0); RD_B(1, 0, bA); STAGE(0, 0, 1, k2);
        BAR(); LGKM0(); SCH0(); PRIO(1); MM(0, 0, bA); PRIO(0); BAR(); SCH0();
        // P6: reads buf1 B-nh1 ; stage (t+2).B1
        RD_B(1, 1, bB); STAGE(0, 1, 1, k2);
        BAR(); LGKM0(); SCH0(); PRIO(1); MM(0, 1, bB); PRIO(0); BAR(); SCH0();
        // P7: reads buf1 A-mh1 ; stage (t+3).B0
        RD_A(1, 1); STAGE(1, 1, 0, k3);
        BAR(); LGKM0(); SCH0(); PRIO(1); MM(1, 1, bB); PRIO(0); BAR(); SCH0();
        // P8: stage (t+3).A0 ; counted vmcnt before next-iter buf0 reads
        STAGE(1, 0, 0, k3);
        BAR(); SCH0(); PRIO(1); MM(1, 0, bA); PRIO(0); VM4(); BAR(); SCH0();
    }

    // ---- epilogue: C[row][col] = acc + bias[col] ----
    float bb[4];
    #pragma unroll
    for (int n = 0; n < 4; ++n) bb[n] = bias[bcol + wn * 64 + n * 16 + fr];
    #pragma unroll
    for (int mi = 0; mi < 8; ++mi) {
        #pragma unroll
        for (int q = 0; q < 4; ++q) {
            int row = brow + wm * 128 + mi * 16 + fq * 4 + q;
            float* crow = C + (size_t)row * NDIM + bcol + wn * 64;
            #pragma unroll
            for (int n = 0; n < 4; ++n)
                crow[n * 16 + fr] = acc[mi][n][q] + bb[n];
        }
    }
}

// ---------- launch ----------
extern "C" void kernel_launch(void* const* d_in, const int* in_sizes, int n_in,
                              void* d_out, int out_size, void* d_ws, size_t ws_size,
                              hipStream_t stream) {
    const float* x = (const float*)d_in[0];
    const float* w = (const float*)d_in[1];
    const float* b = (const float*)d_in[2];
    float* out = (float*)d_out;

    unsigned short* xb = (unsigned short*)d_ws;                         // 32 MB
    unsigned short* wq = xb + (size_t)NDIM * KDIM;                      // 32 MB

    xcvt_kernel<<<MDIM * KDIM / 4 / 256, 256, 0, stream>>>(x, xb);
    wdeq_kernel<<<NDIM * (KDIM / 128) / 4, 256, 0, stream>>>(w, wq);
    gemm256<<<(MDIM / BM) * (NDIM / BN), 512, 0, stream>>>(xb, wq, b, out);
}

// Round 3
// 157.512 us; speedup vs baseline: 1.1884x; 1.0020x over previous
//
#include <hip/hip_runtime.h>
#include <hip/hip_bf16.h>
#include <stdint.h>

#define KDIM 4096
#define NDIM 4096
#define MDIM 4096
#define BM 256
#define BN 256
#define BK 64

typedef __attribute__((ext_vector_type(8))) short bf16x8;
typedef __attribute__((ext_vector_type(4))) float f32x4;

// ---------- helpers ----------

__device__ __forceinline__ unsigned short bf16bits(float f) {
    union { float f; uint32_t u; } c; c.f = f;
    uint32_t u = c.u;
    uint32_t r = (u + 0x7fffu + ((u >> 16) & 1u)) >> 16;   // RNE
    return (unsigned short)r;
}

// Faithful FP4 E2M1 quant-dequant (matches reference float math).
__device__ __forceinline__ float fp4qd(float x) {
    float a = fabsf(x);
    if (a == 0.0f) return 0.0f;
    float e = floorf(log2f(a));
    float val;
    if (e < 0.0f) {                       // subnormal path
        float mant = fminf(fmaxf(rintf(a * 2.0f), 0.0f), 1.0f);
        val = mant * 0.5f;
    } else {
        float ec = fminf(e, 2.0f);
        float p  = exp2f(ec);             // exact: 1,2,4
        float mant = fminf(fmaxf(rintf((a / p - 1.0f) * 2.0f), 0.0f), 1.0f);
        val = (1.0f + 0.5f * mant) * p;
    }
    return (x < 0.0f) ? -val : val;
}

__device__ __forceinline__ void gld16(void* lds, const void* g) {
    __builtin_amdgcn_global_load_lds(
        (const __attribute__((address_space(1))) unsigned int*)g,
        (__attribute__((address_space(3))) unsigned int*)lds,
        16, 0, 0);
}

// ---------- kernel 1: weight quant-dequant -> bf16 ----------
__global__ __launch_bounds__(256) void wdeq_kernel(const float* __restrict__ W,
                                                   unsigned short* __restrict__ Wq) {
    int grp = blockIdx.x * 4 + (threadIdx.x >> 6);
    int l = threadIdx.x & 63;
    const float* gp = W + (size_t)grp * 128 + l * 2;
    float2 v = *(const float2*)gp;
    float am = fmaxf(fabsf(v.x), fabsf(v.y));
    #pragma unroll
    for (int s = 32; s; s >>= 1) am = fmaxf(am, __shfl_xor(am, s));
    float scale = (am == 0.0f) ? 1.0f : am / 6.0f;
    float q0 = fp4qd(v.x / scale) * scale;
    float q1 = fp4qd(v.y / scale) * scale;
    ushort2 o;
    o.x = bf16bits(q0);
    o.y = bf16bits(q1);
    *(ushort2*)(Wq + (size_t)grp * 128 + l * 2) = o;
}

// ---------- kernel 2: x f32 -> bf16 ----------
__global__ __launch_bounds__(256) void xcvt_kernel(const float* __restrict__ X,
                                                   unsigned short* __restrict__ Xb) {
    size_t i = (size_t)(blockIdx.x * 256 + threadIdx.x) * 4;
    float4 v = *(const float4*)(X + i);
    ushort4 o;
    o.x = bf16bits(v.x); o.y = bf16bits(v.y);
    o.z = bf16bits(v.z); o.w = bf16bits(v.w);
    *(ushort4*)(Xb + i) = o;
}

// ---------- kernel 3: 256x256-tile 8-phase GEMM  C = A @ B^T + bias ----------
// A: [M][K] bf16, B: [N][K] bf16, C: [M][N] f32.
// 8 waves (2M x 4N), per-wave 128x64 output, acc[8][4] of 16x16 frags.
// LDS: [buf][op][slab(64 rows)][8KB], 128 KiB, 1 block/CU.
// Staging unit = 64-row slab = 1 x global_load_lds(16B), chunk-XOR swizzled.
// Ledger (iter I computes tiles 2I->buf0, 2I+1->buf1; 2 loads/phase):
//   P1: (2I+1).A1s,A3s   P2: (2I+2).A0s,A2s  P3: (2I+2).B0s,B1s
//   P4: (2I+2).B2s,B3s + VM6                 P5: (2I+2).A1s,A3s
//   P6: (2I+3).A0s,A2s   P7: (2I+3).B0s,B1s  P8: (2I+3).B2s,B3s + VM6
// Every region staged only after its last reader's phase-end barrier;
// every vmcnt(6) drains exactly the next-needed tile (FIFO-verified).

#define BAR()    __builtin_amdgcn_s_barrier()
#define LGKM0()  asm volatile("s_waitcnt lgkmcnt(0)" ::: "memory")
#define LGKM8()  asm volatile("s_waitcnt lgkmcnt(8)" ::: "memory")
#define VM6()    asm volatile("s_waitcnt vmcnt(6)" ::: "memory")
#define SCH0()   __builtin_amdgcn_sched_barrier(0)
#define PRIO(x)  __builtin_amdgcn_s_setprio(x)

__global__ __launch_bounds__(512, 2) void gemm256(const unsigned short* __restrict__ A,
                                                  const unsigned short* __restrict__ B,
                                                  const float* __restrict__ bias,
                                                  float* __restrict__ C) {
    __shared__ __attribute__((aligned(16))) char smem[2][2][4][8192];
    char* sm = (char*)&smem[0][0][0][0];

    const int t = threadIdx.x;
    const int l = t & 63;
    const int w = __builtin_amdgcn_readfirstlane(t >> 6);  // 0..7
    const int wm = w >> 2;        // 0..1  (M half)
    const int wn = w & 3;         // 0..3  (N quarter)

    // bijective XCD swizzle (256 blocks, 8 XCDs)
    int bid = blockIdx.x;
    int swz = (bid & 7) * 32 + (bid >> 3);
    int brow = (swz >> 4) * BM;
    int bcol = (swz & 15) * BN;

    // ---- staging addresses (pre-swizzled global source, linear LDS dest) ----
    const int lr8  = l >> 3;                 // row in 8-row slab
    const int slot = l & 7;
    const int scol = (slot ^ lr8) << 3;      // swizzled source col (elements)
    const unsigned short* pA = A + (size_t)(brow + w * 8 + lr8) * KDIM + scol;
    const unsigned short* pB = B + (size_t)(bcol + w * 8 + lr8) * KDIM + scol;

    // stage one 64-row slab of op (0=A,1=B) into buffer b at K-tile kt
#define STAGE64(b, op, slab, kt) do {                                          \
    const unsigned short* _s = ((op) ? pB : pA)                                \
        + (size_t)((slab) * 64) * KDIM + (size_t)(kt) * BK;                    \
    gld16(sm + (b) * 65536 + (op) * 32768 + (slab) * 8192 + w * 1024, _s);     \
} while (0)

    // ---- fragment read addressing ----
    const int fr  = l & 15;
    const int fq  = l >> 4;
    const int kx0 = ((fq    ) ^ (fr & 7)) << 4;   // ks=0 swizzled chunk byte
    const int kx1 = ((fq + 4) ^ (fr & 7)) << 4;   // ks=1
    const int frA = fr * 128;

#define RD_A(b, mh) do {                                                        \
    const char* _p = sm + (b) * 65536 + wm * 16384 + (mh) * 8192 + frA;         \
    _Pragma("unroll")                                                           \
    for (int m = 0; m < 4; ++m) {                                               \
        a[m][0] = *(const bf16x8*)(_p + m * 2048 + kx0);                        \
        a[m][1] = *(const bf16x8*)(_p + m * 2048 + kx1);                        \
    }                                                                           \
} while (0)

#define RD_B(b, nh, arr) do {                                                   \
    const char* _p = sm + (b) * 65536 + 32768 + wn * 8192 + (nh) * 4096 + frA;  \
    _Pragma("unroll")                                                           \
    for (int n = 0; n < 2; ++n) {                                               \
        arr[n][0] = *(const bf16x8*)(_p + n * 2048 + kx0);                      \
        arr[n][1] = *(const bf16x8*)(_p + n * 2048 + kx1);                      \
    }                                                                           \
} while (0)

#define MM(mh, nh, arr)                                                         \
    _Pragma("unroll")                                                           \
    for (int m = 0; m < 4; ++m)                                                 \
        _Pragma("unroll")                                                       \
        for (int n = 0; n < 2; ++n)                                             \
            _Pragma("unroll")                                                   \
            for (int ks = 0; ks < 2; ++ks)                                      \
                acc[(mh) * 4 + m][(nh) * 2 + n] =                               \
                    __builtin_amdgcn_mfma_f32_16x16x32_bf16(                    \
                        a[m][ks], arr[n][ks], acc[(mh) * 4 + m][(nh) * 2 + n],  \
                        0, 0, 0);

    f32x4 acc[8][4];
    #pragma unroll
    for (int m = 0; m < 8; ++m)
        #pragma unroll
        for (int n = 0; n < 4; ++n)
            acc[m][n] = f32x4{0.f, 0.f, 0.f, 0.f};

    bf16x8 a[4][2], bA[2][2], bB[2][2];

    // ---- prologue: tile0 all 8 slabs + tile1 first 6 slabs ----
    STAGE64(0, 0, 0, 0); STAGE64(0, 0, 2, 0); STAGE64(0, 1, 0, 0); STAGE64(0, 1, 1, 0);
    STAGE64(0, 1, 2, 0); STAGE64(0, 1, 3, 0); STAGE64(0, 0, 1, 0); STAGE64(0, 0, 3, 0);
    STAGE64(1, 0, 0, 1); STAGE64(1, 0, 2, 1); STAGE64(1, 1, 0, 1); STAGE64(1, 1, 1, 1);
    STAGE64(1, 1, 2, 1); STAGE64(1, 1, 3, 1);
    VM6();               // drains tile0 fully; tile1's 6 slabs stay in flight
    BAR();

    // ---- main loop ----
    for (int it = 0; it < 32; ++it) {
        const int k1 = 2 * it + 1;
        const int k2 = (2 * it + 2) & 63;   // wrap on last iter (never read)
        const int k3 = (2 * it + 3) & 63;

        // P1: read buf0 A-mh0 + B-nh0
        RD_A(0, 0); RD_B(0, 0, bA);
        STAGE64(1, 0, 1, k1); STAGE64(1, 0, 3, k1);
        LGKM8();
        BAR(); LGKM0(); SCH0();
        PRIO(1); MM(0, 0, bA); PRIO(0);
        BAR();
        // P2: read buf0 B-nh1
        RD_B(0, 1, bB);
        STAGE64(0, 0, 0, k2); STAGE64(0, 0, 2, k2);
        BAR(); LGKM0(); SCH0();
        PRIO(1); MM(0, 1, bB); PRIO(0);
        BAR();
        // P3: read buf0 A-mh1
        RD_A(0, 1);
        STAGE64(0, 1, 0, k2); STAGE64(0, 1, 1, k2);
        BAR(); LGKM0(); SCH0();
        PRIO(1); MM(1, 1, bB); PRIO(0);
        BAR();
        // P4: no reads; counted vmcnt -> buf1 (tile 2I+1) fully landed
        STAGE64(0, 1, 2, k2); STAGE64(0, 1, 3, k2);
        BAR(); SCH0();
        PRIO(1); MM(1, 0, bA); PRIO(0);
        VM6();
        BAR();
        // P5: read buf1 A-mh0 + B-nh0
        RD_A(1, 0); RD_B(1, 0, bA);
        STAGE64(0, 0, 1, k2); STAGE64(0, 0, 3, k2);
        LGKM8();
        BAR(); LGKM0(); SCH0();
        PRIO(1); MM(0, 0, bA); PRIO(0);
        BAR();
        // P6: read buf1 B-nh1
        RD_B(1, 1, bB);
        STAGE64(1, 0, 0, k3); STAGE64(1, 0, 2, k3);
        BAR(); LGKM0(); SCH0();
        PRIO(1); MM(0, 1, bB); PRIO(0);
        BAR();
        // P7: read buf1 A-mh1
        RD_A(1, 1);
        STAGE64(1, 1, 0, k3); STAGE64(1, 1, 1, k3);
        BAR(); LGKM0(); SCH0();
        PRIO(1); MM(1, 1, bB); PRIO(0);
        BAR();
        // P8: no reads; counted vmcnt -> buf0 (tile 2I+2) fully landed
        STAGE64(1, 1, 2, k3); STAGE64(1, 1, 3, k3);
        BAR(); SCH0();
        PRIO(1); MM(1, 0, bA); PRIO(0);
        VM6();
        BAR();
    }

    // ---- epilogue: C[row][col] = acc + bias[col] ----
    float bb[4];
    #pragma unroll
    for (int n = 0; n < 4; ++n) bb[n] = bias[bcol + wn * 64 + n * 16 + fr];
    #pragma unroll
    for (int mi = 0; mi < 8; ++mi) {
        #pragma unroll
        for (int q = 0; q < 4; ++q) {
            int row = brow + wm * 128 + mi * 16 + fq * 4 + q;
            float* crow = C + (size_t)row * NDIM + bcol + wn * 64;
            #pragma unroll
            for (int n = 0; n < 4; ++n)
                crow[n * 16 + fr] = acc[mi][n][q] + bb[n];
        }
    }
}

// ---------- launch ----------
extern "C" void kernel_launch(void* const* d_in, const int* in_sizes, int n_in,
                              void* d_out, int out_size, void* d_ws, size_t ws_size,
                              hipStream_t stream) {
    const float* x = (const float*)d_in[0];
    const float* w = (const float*)d_in[1];
    const float* b = (const float*)d_in[2];
    float* out = (float*)d_out;

    unsigned short* xb = (unsigned short*)d_ws;                         // 32 MB
    unsigned short* wq = xb + (size_t)NDIM * KDIM;                      // 32 MB

    xcvt_kernel<<<MDIM * KDIM / 4 / 256, 256, 0, stream>>>(x, xb);
    wdeq_kernel<<<NDIM * (KDIM / 128) / 4, 256, 0, stream>>>(w, wq);
    gemm256<<<(MDIM / BM) * (NDIM / BN), 512, 0, stream>>>(xb, wq, b, out);
}